// Round 5
// baseline (441.190 us; speedup 1.0000x reference)
//
#include <hip/hip_runtime.h>

#define P 10
#define PM 9
// lower-triangular flat index, requires a>=b
#define TRI(a,b) ((a)*((a)+1)/2 + (b))

typedef float vfloat4 __attribute__((ext_vector_type(4)));

__device__ __forceinline__ int tri_sym(int a, int b) { return a >= b ? TRI(a, b) : TRI(b, a); }

// ---- load Theta[b] lower triangle (float4 loads; upper-tri lanes DCE) ----
__device__ __forceinline__ void load_theta(const float* __restrict__ Theta, int b, float* __restrict__ Tl)
{
    const float4* tp = reinterpret_cast<const float4*>(Theta + (size_t)b * (P * P));
#pragma unroll
    for (int q = 0; q < (P * P) / 4; q++) {
        float4 t = tp[q];
        float c4[4] = {t.x, t.y, t.z, t.w};
#pragma unroll
        for (int c = 0; c < 4; c++) {
            int e = 4 * q + c;
            int i = e / P, j = e % P;
            if (i >= j) Tl[TRI(i, j)] = c4[c];
        }
    }
}

// ---- R1-structure inversion: Tl(chol, inverted diag) -> Li -> Wl ----
__device__ __forceinline__ void invert_spd(float* __restrict__ Tl, float* __restrict__ Wl)
{
    // Cholesky; diagonal stores 1/L[j][j] (rsq: no divides, no sqrt)
#pragma unroll
    for (int j = 0; j < P; j++) {
        float s = Tl[TRI(j, j)];
#pragma unroll
        for (int k = 0; k < j; k++) s -= Tl[TRI(j, k)] * Tl[TRI(j, k)];
        float ilj = __builtin_amdgcn_rsqf(s);
        Tl[TRI(j, j)] = ilj;
#pragma unroll
        for (int i = j + 1; i < P; i++) {
            float s2 = Tl[TRI(i, j)];
#pragma unroll
            for (int k = 0; k < j; k++) s2 -= Tl[TRI(i, k)] * Tl[TRI(j, k)];
            Tl[TRI(i, j)] = s2 * ilj;
        }
    }
    // Li = L^-1 (separate array, like R1)
    float Li[55];
#pragma unroll
    for (int j = 0; j < P; j++) {
        Li[TRI(j, j)] = Tl[TRI(j, j)];                 // already 1/L[j][j]
#pragma unroll
        for (int i = j + 1; i < P; i++) {
            float s = Tl[TRI(i, j)] * Li[TRI(j, j)];
#pragma unroll
            for (int k = j + 1; k < i; k++) s += Tl[TRI(i, k)] * Li[TRI(k, j)];
            Li[TRI(i, j)] = -s * Tl[TRI(i, i)];        // * 1/L[i][i]
        }
    }
    // W = Li^T * Li (lower triangle)
#pragma unroll
    for (int i = 0; i < P; i++)
#pragma unroll
        for (int j = 0; j <= i; j++) {
            float s = 0.f;
#pragma unroll
            for (int k = i; k < P; k++) s += Li[TRI(k, i)] * Li[TRI(k, j)];
            Wl[TRI(i, j)] = s;
        }
}

// One sweep of P column updates. FINAL=true: skip last column's dead W update.
template<bool FINAL>
__device__ __forceinline__ void sweep(float* __restrict__ Wl, float* __restrict__ diag,
                                      const float* __restrict__ nv)
{
#pragma unroll
    for (int col = 0; col < P; col++) {
        float v_[PM], w12[PM], y_[PM];
#pragma unroll
        for (int t = 0; t < PM; t++) v_[t] = nv[col * PM + t];   // wave-uniform -> s_load
        float w22 = Wl[TRI(col, col)];
#pragma unroll
        for (int t = 0; t < PM; t++) {
            int it = t < col ? t : t + 1;
            w12[t] = Wl[tri_sym(it, col)];
        }
        // y = W11 * v
#pragma unroll
        for (int t = 0; t < PM; t++) {
            int it = t < col ? t : t + 1;
            float s = 0.f;
#pragma unroll
            for (int u = 0; u < PM; u++) {
                int iu = u < col ? u : u + 1;
                s += Wl[tri_sym(it, iu)] * v_[u];
            }
            y_[t] = s;
        }
        float d = 0.f, schur = 0.f;
#pragma unroll
        for (int t = 0; t < PM; t++) { d += w12[t] * v_[t]; schur += v_[t] * y_[t]; }
        float t22n = 1.0f + schur;
        diag[col] = t22n;
        if (FINAL && col == P - 1) return;
        // u = inv_T11*v = y - (d/w22)*w12 ; s1 = v^T u (overwrite y_)
        float dw = d * __builtin_amdgcn_rcpf(w22);
        float s1 = 0.f;
#pragma unroll
        for (int t = 0; t < PM; t++) { y_[t] = y_[t] - dw * w12[t]; s1 += v_[t] * y_[t]; }
        float w22n = __builtin_amdgcn_rcpf(t22n - s1);
#pragma unroll
        for (int t = 0; t < PM; t++) y_[t] = -w22n * y_[t];      // y_ = w12n
        float a = -__builtin_amdgcn_rcpf(w22);
#pragma unroll
        for (int t = 0; t < PM; t++) {
            int it = t < col ? t : t + 1;
            float pa = a * w12[t];
            float pb = w22n * y_[t];
#pragma unroll
            for (int u2 = 0; u2 <= t; u2++) {
                int iu = u2 < col ? u2 : u2 + 1;
                Wl[TRI(it, iu)] += pa * w12[u2] + pb * y_[u2];
            }
        }
#pragma unroll
        for (int t = 0; t < PM; t++) {
            int it = t < col ? t : t + 1;
            Wl[tri_sym(it, col)] = y_[t];
        }
        Wl[TRI(col, col)] = w22n;
    }
}

__device__ __forceinline__ void store_out(float* __restrict__ out, int b,
                                          const float* __restrict__ diag,
                                          const float* __restrict__ nl)
{
    vfloat4* op = reinterpret_cast<vfloat4*>(out + (size_t)b * (P * P));
#pragma unroll
    for (int q = 0; q < (P * P) / 4; q++) {
        float ov[4];
#pragma unroll
        for (int c = 0; c < 4; c++) {
            int e = 4 * q + c; int i = e / P, j = e % P;
            ov[c] = (i == j) ? diag[i] : nl[(i > j ? i : j) * PM + (i < j ? i : j)];
        }
        vfloat4 o = {ov[0], ov[1], ov[2], ov[3]};
        __builtin_nontemporal_store(o, op + q);   // never re-read; keep L3 for input
    }
}

// K==1 specialization: zero runtime loops -> every array index is a constant.
__global__ __launch_bounds__(256, 1)
void spodnet_k1(const float* __restrict__ Theta, const float* __restrict__ noise,
                float* __restrict__ out, int B)
{
    int b = blockIdx.x * blockDim.x + threadIdx.x;
    if (b >= B) return;
    float Tl[55];
    load_theta(Theta, b, Tl);
    float Wl[55];
    invert_spd(Tl, Wl);
    float diag[P];
    sweep<true>(Wl, diag, noise);
    store_out(out, b, diag, noise);
}

// generic K fallback (not used when K==1)
__global__ __launch_bounds__(256, 1)
void spodnet_gen(const float* __restrict__ Theta, const float* __restrict__ noise,
                 float* __restrict__ out, int B, int K)
{
    int b = blockIdx.x * blockDim.x + threadIdx.x;
    if (b >= B) return;
    float Tl[55];
    load_theta(Theta, b, Tl);
    float Wl[55];
    invert_spd(Tl, Wl);
    float diag[P];
    for (int k = 0; k < K - 1; k++)
        sweep<false>(Wl, diag, noise + (size_t)k * P * PM);
    sweep<true>(Wl, diag, noise + (size_t)(K - 1) * P * PM);
    store_out(out, b, diag, noise + (size_t)(K - 1) * P * PM);
}

extern "C" void kernel_launch(void* const* d_in, const int* in_sizes, int n_in,
                              void* d_out, int out_size, void* d_ws, size_t ws_size,
                              hipStream_t stream) {
    const float* Theta = (const float*)d_in[0];
    const float* noise = (const float*)d_in[1];
    float* out = (float*)d_out;
    int B = in_sizes[0] / (P * P);
    int K = in_sizes[1] / (P * PM);
    int threads = 256;
    int blocks = (B + threads - 1) / threads;
    if (K == 1)
        hipLaunchKernelGGL(spodnet_k1, dim3(blocks), dim3(threads), 0, stream,
                           Theta, noise, out, B);
    else
        hipLaunchKernelGGL(spodnet_gen, dim3(blocks), dim3(threads), 0, stream,
                           Theta, noise, out, B, K);
}

// Round 6
// 440.324 us; speedup vs baseline: 1.0020x; 1.0020x over previous
//
#include <hip/hip_runtime.h>

#define P 10
#define PM 9
// lower-triangular flat index, requires a>=b
#define TRI(a,b) ((a)*((a)+1)/2 + (b))

typedef float vfloat4 __attribute__((ext_vector_type(4)));

__device__ __forceinline__ int tri_sym(int a, int b) { return a >= b ? TRI(a, b) : TRI(b, a); }

// ---- load Theta[b] lower triangle (float4 loads; upper-tri lanes DCE) ----
__device__ __forceinline__ void load_theta(const float* __restrict__ Theta, int b, float* __restrict__ Tl)
{
    const float4* tp = reinterpret_cast<const float4*>(Theta + (size_t)b * (P * P));
#pragma unroll
    for (int q = 0; q < (P * P) / 4; q++) {
        float4 t = tp[q];
        float c4[4] = {t.x, t.y, t.z, t.w};
#pragma unroll
        for (int c = 0; c < 4; c++) {
            int e = 4 * q + c;
            int i = e / P, j = e % P;
            if (i >= j) Tl[TRI(i, j)] = c4[c];
        }
    }
}

// ---- inversion: Tl(chol, inverted diag) -> Li -> Wl ----
__device__ __forceinline__ void invert_spd(float* __restrict__ Tl, float* __restrict__ Wl)
{
    // Cholesky; diagonal stores 1/L[j][j] (rsq: no divides, no sqrt)
#pragma unroll
    for (int j = 0; j < P; j++) {
        float s = Tl[TRI(j, j)];
#pragma unroll
        for (int k = 0; k < j; k++) s -= Tl[TRI(j, k)] * Tl[TRI(j, k)];
        float ilj = __builtin_amdgcn_rsqf(s);
        Tl[TRI(j, j)] = ilj;
#pragma unroll
        for (int i = j + 1; i < P; i++) {
            float s2 = Tl[TRI(i, j)];
#pragma unroll
            for (int k = 0; k < j; k++) s2 -= Tl[TRI(i, k)] * Tl[TRI(j, k)];
            Tl[TRI(i, j)] = s2 * ilj;
        }
    }
    // Li = L^-1
    float Li[55];
#pragma unroll
    for (int j = 0; j < P; j++) {
        Li[TRI(j, j)] = Tl[TRI(j, j)];                 // already 1/L[j][j]
#pragma unroll
        for (int i = j + 1; i < P; i++) {
            float s = Tl[TRI(i, j)] * Li[TRI(j, j)];
#pragma unroll
            for (int k = j + 1; k < i; k++) s += Tl[TRI(i, k)] * Li[TRI(k, j)];
            Li[TRI(i, j)] = -s * Tl[TRI(i, i)];        // * 1/L[i][i]
        }
    }
    // W = Li^T * Li (lower triangle)
#pragma unroll
    for (int i = 0; i < P; i++)
#pragma unroll
        for (int j = 0; j <= i; j++) {
            float s = 0.f;
#pragma unroll
            for (int k = i; k < P; k++) s += Li[TRI(k, i)] * Li[TRI(k, j)];
            Wl[TRI(i, j)] = s;
        }
}

// Full column update (no early exits — keeps the caller's col-loop single-exit
// so LLVM fully unrolls it and SROA promotes Wl to registers; see rule #20).
__device__ __forceinline__ void col_update(float* __restrict__ Wl, float* __restrict__ diag,
                                           const float* __restrict__ nv, int col)
{
    float v_[PM], w12[PM], y_[PM];
#pragma unroll
    for (int t = 0; t < PM; t++) v_[t] = nv[col * PM + t];   // wave-uniform -> s_load
    float w22 = Wl[TRI(col, col)];
#pragma unroll
    for (int t = 0; t < PM; t++) {
        int it = t < col ? t : t + 1;
        w12[t] = Wl[tri_sym(it, col)];
    }
    // y = W11 * v
#pragma unroll
    for (int t = 0; t < PM; t++) {
        int it = t < col ? t : t + 1;
        float s = 0.f;
#pragma unroll
        for (int u = 0; u < PM; u++) {
            int iu = u < col ? u : u + 1;
            s += Wl[tri_sym(it, iu)] * v_[u];
        }
        y_[t] = s;
    }
    float d = 0.f, schur = 0.f;
#pragma unroll
    for (int t = 0; t < PM; t++) { d += w12[t] * v_[t]; schur += v_[t] * y_[t]; }
    float t22n = 1.0f + schur;
    diag[col] = t22n;
    // u = inv_T11*v = y - (d/w22)*w12 ; s1 = v^T u (overwrite y_)
    float dw = d * __builtin_amdgcn_rcpf(w22);
    float s1 = 0.f;
#pragma unroll
    for (int t = 0; t < PM; t++) { y_[t] = y_[t] - dw * w12[t]; s1 += v_[t] * y_[t]; }
    float w22n = __builtin_amdgcn_rcpf(t22n - s1);
#pragma unroll
    for (int t = 0; t < PM; t++) y_[t] = -w22n * y_[t];      // y_ = w12n
    float a = -__builtin_amdgcn_rcpf(w22);
#pragma unroll
    for (int t = 0; t < PM; t++) {
        int it = t < col ? t : t + 1;
        float pa = a * w12[t];
        float pb = w22n * y_[t];
#pragma unroll
        for (int u2 = 0; u2 <= t; u2++) {
            int iu = u2 < col ? u2 : u2 + 1;
            Wl[TRI(it, iu)] += pa * w12[u2] + pb * y_[u2];
        }
    }
#pragma unroll
    for (int t = 0; t < PM; t++) {
        int it = t < col ? t : t + 1;
        Wl[tri_sym(it, col)] = y_[t];
    }
    Wl[TRI(col, col)] = w22n;
}

// One sweep. FINAL=true: cols 0..P-2 full, then col P-1 computes t22n only
// (its W-update is dead). Single-exit loop + constexpr tail.
template<bool FINAL>
__device__ __forceinline__ void sweep(float* __restrict__ Wl, float* __restrict__ diag,
                                      const float* __restrict__ nv)
{
    constexpr int NF = FINAL ? (P - 1) : P;
#pragma unroll
    for (int col = 0; col < NF; col++)
        col_update(Wl, diag, nv, col);
    if constexpr (FINAL) {
        // col = P-1: idx = 0..8, it == t
        float v_[PM];
#pragma unroll
        for (int t = 0; t < PM; t++) v_[t] = nv[(P - 1) * PM + t];
        float schur = 0.f;
#pragma unroll
        for (int t = 0; t < PM; t++) {
            float s = 0.f;
#pragma unroll
            for (int u = 0; u < PM; u++) s += Wl[tri_sym(t, u)] * v_[u];
            schur += v_[t] * s;
        }
        diag[P - 1] = 1.0f + schur;
    }
}

__device__ __forceinline__ void store_out(float* __restrict__ out, int b,
                                          const float* __restrict__ diag,
                                          const float* __restrict__ nl)
{
    vfloat4* op = reinterpret_cast<vfloat4*>(out + (size_t)b * (P * P));
#pragma unroll
    for (int q = 0; q < (P * P) / 4; q++) {
        float ov[4];
#pragma unroll
        for (int c = 0; c < 4; c++) {
            int e = 4 * q + c; int i = e / P, j = e % P;
            ov[c] = (i == j) ? diag[i] : nl[(i > j ? i : j) * PM + (i < j ? i : j)];
        }
        vfloat4 o = {ov[0], ov[1], ov[2], ov[3]};
        __builtin_nontemporal_store(o, op + q);   // never re-read; keep L3 for input
    }
}

// K==1 specialization: zero runtime loops.
__global__ __launch_bounds__(256, 1)
void spodnet_k1(const float* __restrict__ Theta, const float* __restrict__ noise,
                float* __restrict__ out, int B)
{
    int b = blockIdx.x * blockDim.x + threadIdx.x;
    if (b >= B) return;
    float Tl[55];
    load_theta(Theta, b, Tl);
    float Wl[55];
    invert_spd(Tl, Wl);
    float diag[P];
    sweep<true>(Wl, diag, noise);
    store_out(out, b, diag, noise);
}

// generic K fallback (not used when K==1)
__global__ __launch_bounds__(256, 1)
void spodnet_gen(const float* __restrict__ Theta, const float* __restrict__ noise,
                 float* __restrict__ out, int B, int K)
{
    int b = blockIdx.x * blockDim.x + threadIdx.x;
    if (b >= B) return;
    float Tl[55];
    load_theta(Theta, b, Tl);
    float Wl[55];
    invert_spd(Tl, Wl);
    float diag[P];
    for (int k = 0; k < K - 1; k++)
        sweep<false>(Wl, diag, noise + (size_t)k * P * PM);
    sweep<true>(Wl, diag, noise + (size_t)(K - 1) * P * PM);
    store_out(out, b, diag, noise + (size_t)(K - 1) * P * PM);
}

extern "C" void kernel_launch(void* const* d_in, const int* in_sizes, int n_in,
                              void* d_out, int out_size, void* d_ws, size_t ws_size,
                              hipStream_t stream) {
    const float* Theta = (const float*)d_in[0];
    const float* noise = (const float*)d_in[1];
    float* out = (float*)d_out;
    int B = in_sizes[0] / (P * P);
    int K = in_sizes[1] / (P * PM);
    int threads = 256;
    int blocks = (B + threads - 1) / threads;
    if (K == 1)
        hipLaunchKernelGGL(spodnet_k1, dim3(blocks), dim3(threads), 0, stream,
                           Theta, noise, out, B);
    else
        hipLaunchKernelGGL(spodnet_gen, dim3(blocks), dim3(threads), 0, stream,
                           Theta, noise, out, B, K);
}